// Round 9
// baseline (135.873 us; speedup 1.0000x reference)
//
#include <hip/hip_runtime.h>

// ---------------------------------------------------------------------------
// Temporal MHA (MI355X/gfx950), B=256, S=176 (8t x 22j), D_in=128, H=8, Hd=32.
//  k0: x,W -> bf16 once (ws).
//  k1: block = (batch-pair, h), 704 thr = 11 waves, 2 blocks/CU.
//   p1: wave w = m-tile w for BOTH batches; W b128 frags read once, reused.
//       Q^T stays in regs (R7-verified k-slot permutation); K,V^T stored to
//       LDS in PERMUTED column order so p2 gathers are single b128 with
//       bank-uniform addressing (structural floor, no conflicts).
//   p2: per batch: S^T = K·Q^T (11 MFMA), mask, exp2-softmax (unnormalized,
//       1/sum in epilogue), P^T in regs, O^T = V^T·P^T (12 MFMA), f32 stores.
// k-slot bijection sigma(q,j) = (j<4 ? q*4+j : 16+q*4+(j-4)); KS col
// s=(c>>2)*8+nt*4+(c&3); VT col s=(w>>1)*32+(c>>2)*8+(w&1)*4+(c&3).
// R9 fix: VT pad zeroing covered physical cols [160,180) but the permuted
// pad slots (logical t' 176..191) land at {164-167,172-175,180-183,188-191};
// stale LDS NaN * 0 = NaN in the g=5 PV MFMA. Now zero all of [160,192).
// ---------------------------------------------------------------------------

#define SEQ    176
#define HD     32
#define DIN    128
#define DMODEL 256

typedef unsigned short ushort_t;
typedef __attribute__((ext_vector_type(8))) short short8;
typedef __attribute__((ext_vector_type(4))) short short4v;
typedef __attribute__((ext_vector_type(4))) float float4v;
typedef __attribute__((ext_vector_type(4))) unsigned short ushort4v;

// ws layout (bytes): WT bf16 [3][8][32][128] @ 0; X16 bf16 [256*176*128] @ 196608
#define WS_WT 0u
#define WS_X  196608u

// LDS (ushort units), total 39936 ush = 79872 B -> 2 blocks/CU
//  WS @ 0      [3][32][136]     = 13056  (W slices, padded, phase 1)
//  KS @ 13056  [2][176][40]     = 14080  (K, permuted cols)
//  VT @ 27136  [2][32][200]     = 12800  (V^T, permuted cols; pad zeroed)
#define SMEM_TOTAL 39936
#define OFF_KS 13056
#define OFF_VT 27136
#define KS_B   7040
#define VT_B   6400

__device__ __forceinline__ ushort_t f2bf(float f) {
    union { float f; unsigned int u; } cv; cv.f = f;
    unsigned int u = cv.u;
    unsigned int rb = 0x7FFFu + ((u >> 16) & 1u);   // RTNE
    return (ushort_t)((u + rb) >> 16);
}

// ---------------- k0: one-shot bf16 conversion ----------------------------
__global__ __launch_bounds__(256)
void k0_conv(const float* __restrict__ x,
             const float* __restrict__ Wq, const float* __restrict__ Wk,
             const float* __restrict__ Wv,
             ushort_t* __restrict__ WT, ushort_t* __restrict__ X16)
{
    int bid = blockIdx.x;
    if (bid < 5632) {
        int f4 = bid * 256 + threadIdx.x;
        float4 v = reinterpret_cast<const float4*>(x)[f4];
        ushort4v o;
        o.x = f2bf(v.x); o.y = f2bf(v.y); o.z = f2bf(v.z); o.w = f2bf(v.w);
        reinterpret_cast<ushort4v*>(X16)[f4] = o;
    } else {
        int idx = (bid - 5632) * 256 + threadIdx.x;   // < 24576
        int e = idx * 4;
        int mat = e >> 15, h = (e >> 12) & 7, n = (e >> 7) & 31, k = e & 127;
        const float* W = (mat == 0) ? Wq : ((mat == 1) ? Wk : Wv);
        ushort4v o;
        o.x = f2bf(W[(k + 0) * DMODEL + h * HD + n]);
        o.y = f2bf(W[(k + 1) * DMODEL + h * HD + n]);
        o.z = f2bf(W[(k + 2) * DMODEL + h * HD + n]);
        o.w = f2bf(W[(k + 3) * DMODEL + h * HD + n]);
        reinterpret_cast<ushort4v*>(WT)[idx] = o;
    }
}

// ---------------- k1: fused attention (2 batches / block) -----------------
__global__ __launch_bounds__(704, 6)
void k1_attn(const ushort_t* __restrict__ X16, const ushort_t* __restrict__ WT,
             const float* __restrict__ bq, const float* __restrict__ bk,
             const float* __restrict__ bv, float* __restrict__ out)
{
    __shared__ ushort_t smem[SMEM_TOTAL];
    ushort_t* WS = smem;                 // [3][32][136]
    ushort_t* KS = smem + OFF_KS;        // [2][176][40] permuted
    ushort_t* VT = smem + OFF_VT;        // [2][32][200] permuted

    const int tid  = threadIdx.x;
    const int lane = tid & 63;
    const int w    = tid >> 6;           // wave 0..10 = m-tile / row-tile
    const int c    = lane & 15;
    const int q    = lane >> 4;
    const int b0   = (blockIdx.x >> 3) * 2;
    const int h    = blockIdx.x & 7;

    // ---- stage W-slice (head h): 1536 chunks of 16 B, 16 chunks per n-row
#pragma unroll
    for (int it = 0; it < 3; ++it) {
        int c8 = tid + it * 704;
        if (c8 < 1536) {
            int mat = c8 >> 9, rem = c8 & 511, n = rem >> 4, kc = rem & 15;
            short8 v = *reinterpret_cast<const short8*>(
                WT + (size_t)(((mat * 8 + h) * 32 + n) * 128 + kc * 8));
            *reinterpret_cast<short8*>(WS + (mat * 32 + n) * 136 + kc * 8) = v;
        }
    }
    // zero ALL of VT physical cols [160,192) for both batches [R9 fix]:
    // permuted pad slots (t' 176..191) interleave through this range; real
    // w=10 data overwrites its interleaved half after barrier 0.
    if (tid < 512) {
        int bb = tid >> 8, rem = tid & 255;
        int row = rem >> 3, ch = rem & 7;
        short4v z = {0, 0, 0, 0};
        *reinterpret_cast<short4v*>(VT + bb * VT_B + row * 200 + 160 + ch * 4) = z;
    }
    __syncthreads();   // barrier 0: cross-wave staging

    // ---- phase 1: QKV for m-tile w, both batches; W frags read once -----
    short8 xf[2][4];
#pragma unroll
    for (int bb = 0; bb < 2; ++bb) {
        const ushort_t* xr = X16 + ((size_t)(b0 + bb) * SEQ + w * 16 + c) * DIN;
#pragma unroll
        for (int kk = 0; kk < 4; ++kk)
            xf[bb][kk] = *reinterpret_cast<const short8*>(xr + kk * 32 + q * 8);
    }

    const float qscale = 0.17677669529663687f * 1.4426950408889634f; // 1/sqrt(32)*log2e
    short8 qf8[2];
    const int skv = (c >> 2) * 8 + (c & 3);          // permuted col base (K)
    const int svt = (w >> 1) * 32 + (c >> 2) * 8 + (w & 1) * 4 + (c & 3); // (V)

#pragma unroll
    for (int jj = 0; jj < 6; ++jj) {
        const int mat = jj >> 1, nt = jj & 1;
        const ushort_t* wrow = WS + (mat * 32 + nt * 16 + c) * 136 + q * 8;
        short8 wf[4];
#pragma unroll
        for (int kk = 0; kk < 4; ++kk)
            wf[kk] = *reinterpret_cast<const short8*>(wrow + kk * 32);

#pragma unroll
        for (int bb = 0; bb < 2; ++bb) {
            float4v acc = {0.f, 0.f, 0.f, 0.f};
            if (mat == 1) {              // K normal: A=x, B=W
#pragma unroll
                for (int kk = 0; kk < 4; ++kk)
                    acc = __builtin_amdgcn_mfma_f32_16x16x32_bf16(xf[bb][kk], wf[kk], acc, 0, 0, 0);
            } else {                     // Q^T / V^T: A=W, B=x
#pragma unroll
                for (int kk = 0; kk < 4; ++kk)
                    acc = __builtin_amdgcn_mfma_f32_16x16x32_bf16(wf[kk], xf[bb][kk], acc, 0, 0, 0);
            }
            if (mat == 0) {
                float4 bb4 = *reinterpret_cast<const float4*>(bq + h * HD + nt * 16 + q * 4);
                qf8[bb][nt * 4 + 0] = (short)f2bf((acc[0] + bb4.x) * qscale);
                qf8[bb][nt * 4 + 1] = (short)f2bf((acc[1] + bb4.y) * qscale);
                qf8[bb][nt * 4 + 2] = (short)f2bf((acc[2] + bb4.z) * qscale);
                qf8[bb][nt * 4 + 3] = (short)f2bf((acc[3] + bb4.w) * qscale);
            } else if (mat == 1) {
                float bia = bk[h * HD + nt * 16 + c];
                ushort_t* ksb = KS + bb * KS_B;
#pragma unroll
                for (int r = 0; r < 4; ++r)
                    ksb[(w * 16 + q * 4 + r) * 40 + skv + nt * 4] = f2bf(acc[r] + bia);
            } else {
                float4 bb4 = *reinterpret_cast<const float4*>(bv + h * HD + nt * 16 + q * 4);
                ushort_t* vtb = VT + bb * VT_B;
#pragma unroll
                for (int r = 0; r < 4; ++r) {
                    float bias_r = (r == 0) ? bb4.x : (r == 1) ? bb4.y : (r == 2) ? bb4.z : bb4.w;
                    float v = acc[r] + bias_r;
                    v = v > 0.f ? v : 0.f;           // ReLU on V
                    vtb[(nt * 16 + q * 4 + r) * 200 + svt] = f2bf(v);
                }
            }
        }
    }
    __syncthreads();   // barrier 1: KS/VT complete

    // ---- phase 2: attention; lane(c,q) owns score column t = w*16+c ----
    const int t_row = w * 16 + c;
    const int lo = (t_row / 22) * 22;    // start of t's 22-joint time block

#pragma unroll
    for (int bb = 0; bb < 2; ++bb) {
        const ushort_t* KSb = KS + bb * KS_B;
        const ushort_t* VTb = VT + bb * VT_B;
        float su = 0.f;
        short8 pf[6];
        pf[5] = (short8){0, 0, 0, 0, 0, 0, 0, 0};   // n=11 pad half stays zero
#pragma unroll
        for (int n = 0; n < 11; ++n) {
            short8 kf = *reinterpret_cast<const short8*>(KSb + (n * 16 + c) * 40 + q * 8);
            float4v s = {0.f, 0.f, 0.f, 0.f};
            s = __builtin_amdgcn_mfma_f32_16x16x32_bf16(kf, qf8[bb], s, 0, 0, 0);
#pragma unroll
            for (int r = 0; r < 4; ++r) {
                int tp = n * 16 + q * 4 + r;
                float sv = (((unsigned)(tp - lo) < 22u) && (tp != t_row)) ? -1e30f : s[r];
                float e = __builtin_amdgcn_exp2f(sv);
                su += e;
                pf[n >> 1][(n & 1) * 4 + r] = (short)f2bf(e);
            }
        }
        su += __shfl_xor(su, 16, 64);    // reduce across the 4 quads
        su += __shfl_xor(su, 32, 64);
        const float invs = 1.0f / su;

        float* ob = out + ((size_t)(b0 + bb) * SEQ + t_row) * DMODEL + h * HD;
#pragma unroll
        for (int mt = 0; mt < 2; ++mt) {
            const ushort_t* vrow = VTb + (mt * 16 + c) * 200;
            float4v o = {0.f, 0.f, 0.f, 0.f};
#pragma unroll
            for (int g = 0; g < 6; ++g) {
                short8 vf = *reinterpret_cast<const short8*>(vrow + g * 32 + q * 8);
                o = __builtin_amdgcn_mfma_f32_16x16x32_bf16(vf, pf[g], o, 0, 0, 0);
            }
            float4 st;
            st.x = o[0] * invs; st.y = o[1] * invs;
            st.z = o[2] * invs; st.w = o[3] * invs;
            *reinterpret_cast<float4*>(ob + mt * 16 + q * 4) = st;
        }
    }
}

extern "C" void kernel_launch(void* const* d_in, const int* in_sizes, int n_in,
                              void* d_out, int out_size, void* d_ws, size_t ws_size,
                              hipStream_t stream) {
    const float* x  = (const float*)d_in[0];
    const float* Wq = (const float*)d_in[1];
    const float* bq = (const float*)d_in[2];
    const float* Wk = (const float*)d_in[3];
    const float* bk = (const float*)d_in[4];
    const float* Wv = (const float*)d_in[5];
    const float* bv = (const float*)d_in[6];
    float* out = (float*)d_out;

    char* ws = (char*)d_ws;
    ushort_t* WT  = (ushort_t*)(ws + WS_WT);
    ushort_t* X16 = (ushort_t*)(ws + WS_X);

    k0_conv<<<dim3(5728), dim3(256), 0, stream>>>(x, Wq, Wk, Wv, WT, X16);
    k1_attn<<<dim3(1024), dim3(704), 0, stream>>>(X16, WT, bq, bk, bv, out);
}